// Round 13
// baseline (107.972 us; speedup 1.0000x reference)
//
#include <hip/hip_runtime.h>
#include <math.h>

#define DIM 128
#define N_PTS 512
#define K_NEIGH 16
#define POS_HID 64
#define ATTN_HID 512

typedef __attribute__((ext_vector_type(8))) short short8;
typedef __attribute__((ext_vector_type(4))) float f32x4;
typedef unsigned short us;
typedef unsigned long long ull;

__device__ __forceinline__ us f2b(float f) {
    unsigned int u = __builtin_bit_cast(unsigned int, f);
    u += 0x7fffu + ((u >> 16) & 1u);          // RNE
    return (us)(u >> 16);
}

__device__ __forceinline__ ull shflx64(ull v, int m) {
    int lo = __shfl_xor((int)(unsigned int)v, m);
    int hi = __shfl_xor((int)(unsigned int)(v >> 32), m);
    return ((ull)(unsigned int)hi << 32) | (unsigned int)lo;
}

// ---------------------------------------------------------------------------
// Kernel A [R9, verified 99.14]: qkv + pack merged.
// Blocks 0..npts/4-1: qkv tiles with inline wqkv->bf16 fragments.
// Blocks npts/4.. : pack aw1/aw2/pw2 -> p1/p2/p3 [R2-proven layout:
// B[k][n] -> lane l=(k/8%4)*16+(n%16), elem j=k%8, frag ks*NT+nt].
// ---------------------------------------------------------------------------
__global__ __launch_bounds__(256)
void qkv_pack_kernel(const float* __restrict__ x,
                     const float* __restrict__ wqkv,
                     const float* __restrict__ aw1,
                     const float* __restrict__ aw2,
                     const float* __restrict__ pw2,
                     float* __restrict__ qkv,
                     us* __restrict__ p1, us* __restrict__ p2,
                     us* __restrict__ p3, int npts) {
    __shared__ __align__(16) us xA[16][136];
    const int tid = threadIdx.x;
    const int nq = npts >> 2;

    if ((int)blockIdx.x >= nq) {
        int t = ((int)blockIdx.x - nq) * 256 + tid;
        if (t < 65536) {                        // aw1: ks 0..3, nt 0..31
            int j = t & 7, l = (t >> 3) & 63, nt = (t >> 9) & 31, ks = t >> 14;
            int k = ks * 32 + (l >> 4) * 8 + j, n = nt * 16 + (l & 15);
            p1[t] = f2b(aw1[k * ATTN_HID + n]);
        } else if (t < 131072) {                // aw2: ch 0..15, nt 0..7
            int u = t - 65536;
            int j = u & 7, l = (u >> 3) & 63, nt = (u >> 9) & 7, ch = u >> 12;
            int k = ch * 32 + (l >> 4) * 8 + j, n = nt * 16 + (l & 15);
            p2[u] = f2b(aw2[k * DIM + n]);
        } else if (t < 139264) {                // pw2: ks 0..1, nt 0..7
            int u = t - 131072;
            int j = u & 7, l = (u >> 3) & 63, nt = (u >> 9) & 7, ks = u >> 12;
            int k = ks * 32 + (l >> 4) * 8 + j, n = nt * 16 + (l & 15);
            p3[u] = f2b(pw2[k * DIM + n]);
        }
        return;
    }

    const int w = tid >> 6, lane = tid & 63, quad = lane >> 4, lq = lane & 15;
    const int n0 = ((int)blockIdx.x >> 2) * 16;
    const int ntb = ((int)blockIdx.x & 3) * 6;
    const int b = n0 >> 9, nn = n0 & (N_PTS - 1);
#pragma unroll
    for (int rr = 0; rr < 8; ++rr) {
        int id = rr * 256 + tid;
        int d = id >> 4, i = id & 15;
        xA[i][d] = f2b(x[(size_t)(b * DIM + d) * N_PTS + nn + i]);
    }
    __syncthreads();
    short8 a[4];
#pragma unroll
    for (int ks = 0; ks < 4; ++ks)
        a[ks] = *(const short8*)&xA[lq][ks * 32 + quad * 8];
#pragma unroll
    for (int i = 0; i < 2; ++i) {
        int nl = w + i * 4;
        if (nl < 6) {
            int nt = ntb + nl;
            f32x4 acc = {0.f, 0.f, 0.f, 0.f};
#pragma unroll
            for (int ks = 0; ks < 4; ++ks) {
                const float* wp = wqkv + (size_t)(ks * 32 + quad * 8) * 384 + nt * 16 + lq;
                short8 bf;
#pragma unroll
                for (int j = 0; j < 8; ++j) bf[j] = (short)f2b(wp[(size_t)j * 384]);
                acc = __builtin_amdgcn_mfma_f32_16x16x32_bf16(a[ks], bf, acc, 0, 0, 0);
            }
#pragma unroll
            for (int r = 0; r < 4; ++r)
                qkv[(size_t)(n0 + quad * 4 + r) * 384 + nt * 16 + lq] = acc[r];
        }
    }
}

// ---------------------------------------------------------------------------
// Fused attention [R13]: R1 zero-split structure (1 wave/point owns all
// work) + COOPERATIVE LDS WEIGHT STAGING in the MLP loop.
// Theory [R7 probe, quantitative]: MLP reads all 256 KB of p1+p2 per wave
// -> 268 MB L2 traffic at 17.4 TB/s effective = 15.4 us ~= measured 15.1.
// Fix: the block's 4 waves read IDENTICAL weights in identical order ->
// stage each chunk's 16 KB into double-buffered LDS wbuf cooperatively
// (4x dwordx4/thread, issue-early/write-late), all waves ds_read_b128 the
// fragments. L2 traffic 268 -> 67 MB. 16 barriers (waves naturally synced
// post-topk). Work ownership untouched (R2/R3/R12 splits all regressed).
// wbuf layout per buf: us [0,4096) = 8 p1 frags (f=ks*2+t, 512 us each),
// [4096,8192) = 8 p2 frags (nt2), mirroring global fragment-linear order.
// ---------------------------------------------------------------------------
__global__ __launch_bounds__(256, 1)
void attn_fused_kernel(const float* __restrict__ pos,
                       const float* __restrict__ qkv,
                       const float* __restrict__ pw1,
                       const float* __restrict__ pb1,
                       const float* __restrict__ pb2,
                       const us* __restrict__ p1,
                       const us* __restrict__ p2,
                       const us* __restrict__ p3,
                       const float* __restrict__ ab1,
                       float* __restrict__ out) {
    __shared__ __align__(16) us hinA[4][16][136];   // 17.4 KB, per-wave
    __shared__ __align__(16) us h1s[4][16][40];     //  5.1 KB, per-wave
    __shared__ int nbrs[4][16];                     //  256 B, per-wave
    __shared__ __align__(16) us wbuf[2][8192];      // 32 KB, weight dbuf

    const int tid = threadIdx.x;
    const int w = tid >> 6, lane = tid & 63, quad = lane >> 4, lq = lane & 15;
    const int g = blockIdx.x * 4 + w, b = g >> 9, n = g & (N_PTS - 1);
    // staging geometry: thread covers p1 frags f0=w, f1=4+w (elem lane) and
    // two 16B slices of the contiguous p2 slab.
    const int f0 = w, f1 = 4 + w;
    const size_t p1o0 = (size_t)(((f0 >> 1) << 5) + (f0 & 1)) * 512 + lane * 8;
    const size_t p1o1 = (size_t)(((f1 >> 1) << 5) + (f1 & 1)) * 512 + lane * 8;

    // ==== hoisted loads: independent of topk, latency hides under it ====
    short8 b3f[2][8];                      // pw2 fragments
#pragma unroll
    for (int ks = 0; ks < 2; ++ks)
#pragma unroll
        for (int nt = 0; nt < 8; ++nt)
            b3f[ks][nt] = *(const short8*)(p3 + (size_t)((ks * 8 + nt) * 64 + lane) * 8);

    float w1x[2][8], w1y[2][8], w1z[2][8], w1b[2][8];   // pos-MLP layer-1 wts
#pragma unroll
    for (int ks = 0; ks < 2; ++ks)
#pragma unroll
        for (int jj = 0; jj < 8; ++jj) {
            int c = ks * 32 + quad * 8 + jj;
            w1x[ks][jj] = pw1[c];
            w1y[ks][jj] = pw1[64 + c];
            w1z[ks][jj] = pw1[128 + c];
            w1b[ks][jj] = pb1[c];
        }

    float qvr[8], pb2r[8], ab1r[32];
#pragma unroll
    for (int nt = 0; nt < 8; ++nt) {
        qvr[nt]  = qkv[(size_t)g * 384 + nt * 16 + lq];
        pb2r[nt] = pb2[nt * 16 + lq];
    }
#pragma unroll
    for (int nt = 0; nt < 32; ++nt) ab1r[nt] = ab1[nt * 16 + lq];

    // ---- top-16: u64 key = (dist_bits<<32)|j, butterfly min [R5-exact] ----
    {
        const float pix = pos[g * 3 + 0], piy = pos[g * 3 + 1], piz = pos[g * 3 + 2];
        float d2[8];
#pragma unroll
        for (int rr = 0; rr < 8; ++rr) {
            int j = rr * 64 + lane;
            float dx = pix - pos[(b * N_PTS + j) * 3 + 0];
            float dy = piy - pos[(b * N_PTS + j) * 3 + 1];
            float dz = piz - pos[(b * N_PTS + j) * 3 + 2];
            d2[rr] = dx * dx + dy * dy + dz * dz;
        }
        for (int r = 0; r < K_NEIGH; ++r) {
            ull key = ~0ULL;
#pragma unroll
            for (int rr = 0; rr < 8; ++rr) {
                unsigned int fb = __builtin_bit_cast(unsigned int, d2[rr]);
                ull k2 = ((ull)fb << 32) | (unsigned int)(rr * 64 + lane);
                key = k2 < key ? k2 : key;
            }
#pragma unroll
            for (int off = 32; off > 0; off >>= 1) {
                ull o = shflx64(key, off);
                key = o < key ? o : key;
            }
            unsigned int jw = (unsigned int)key;      // uniform post-butterfly
            if (lane == 0) nbrs[w][r] = (int)jw;
            if (lane == (int)(jw & 63)) d2[jw >> 6] = __builtin_inff();
        }
    }

    // ---- pos-MLP hidden -> A-frags (k = ks*32 + quad*8 + jj) ----
    short8 pha[2];
    {
        const int jn = nbrs[w][lq];
        float rx = pos[g * 3 + 0] - pos[(b * N_PTS + jn) * 3 + 0];
        float ry = pos[g * 3 + 1] - pos[(b * N_PTS + jn) * 3 + 1];
        float rz = pos[g * 3 + 2] - pos[(b * N_PTS + jn) * 3 + 2];
#pragma unroll
        for (int ks = 0; ks < 2; ++ks) {
            short8 f;
#pragma unroll
            for (int jj = 0; jj < 8; ++jj) {
                float h = rx * w1x[ks][jj] + ry * w1y[ks][jj] + rz * w1z[ks][jj] + w1b[ks][jj];
                f[jj] = (short)f2b(fmaxf(h, 0.f));
            }
            pha[ks] = f;
        }
    }

    // ---- pe = ph @ pw2 + pb2 (M=16,K=64,N=128) ----
    f32x4 pe[8];
#pragma unroll
    for (int nt = 0; nt < 8; ++nt) {
        f32x4 acc = {0.f, 0.f, 0.f, 0.f};
        acc = __builtin_amdgcn_mfma_f32_16x16x32_bf16(pha[0], b3f[0][nt], acc, 0, 0, 0);
        acc = __builtin_amdgcn_mfma_f32_16x16x32_bf16(pha[1], b3f[1][nt], acc, 0, 0, 0);
#pragma unroll
        for (int r = 0; r < 4; ++r) pe[nt][r] = acc[r] + pb2r[nt];
    }

    // ---- hin = q_i - k_j + pe -> LDS (bf16 A-layout); vg = v_j + pe ----
    f32x4 vg[8];
    {
        int jr[4];
#pragma unroll
        for (int r = 0; r < 4; ++r) jr[r] = nbrs[w][quad * 4 + r];
#pragma unroll
        for (int nt = 0; nt < 8; ++nt) {
            int d = nt * 16 + lq;
#pragma unroll
            for (int r = 0; r < 4; ++r) {
                const float* kv = qkv + (size_t)(b * N_PTS + jr[r]) * 384;
                float pp = pe[nt][r];
                hinA[w][quad * 4 + r][d] = f2b(qvr[nt] - kv[128 + d] + pp);
                vg[nt][r] = kv[256 + d] + pp;
            }
        }
    }

    // ---- MLP over 16 chunks with LDS-staged weights [R13] ----
    short8 a1f[4];
#pragma unroll
    for (int ks = 0; ks < 4; ++ks)
        a1f[ks] = *(const short8*)&hinA[w][lq][ks * 32 + quad * 8];

    f32x4 c2[8];
#pragma unroll
    for (int nt = 0; nt < 8; ++nt) c2[nt] = (f32x4){0.f, 0.f, 0.f, 0.f};

    // prologue: stage chunk 0 into wbuf[0]
    {
        short8 s0 = *(const short8*)(p1 + p1o0);
        short8 s1 = *(const short8*)(p1 + p1o1);
        short8 s2 = *(const short8*)(p2 + (size_t)tid * 8);
        short8 s3 = *(const short8*)(p2 + 2048 + (size_t)tid * 8);
        *(short8*)&wbuf[0][f0 * 512 + lane * 8] = s0;
        *(short8*)&wbuf[0][f1 * 512 + lane * 8] = s1;
        *(short8*)&wbuf[0][4096 + tid * 8] = s2;
        *(short8*)&wbuf[0][4096 + 2048 + tid * 8] = s3;
    }
    __syncthreads();

#pragma unroll
    for (int ch = 0; ch < 16; ++ch) {
        const int cb = ch & 1, nb = cb ^ 1;
        // (1) issue next chunk's staging loads early (latency hides under MFMA)
        short8 s0, s1, s2, s3;
        if (ch < 15) {
            const int cc = ch + 1;
            s0 = *(const short8*)(p1 + (size_t)cc * 1024 + p1o0);
            s1 = *(const short8*)(p1 + (size_t)cc * 1024 + p1o1);
            s2 = *(const short8*)(p2 + (size_t)cc * 4096 + tid * 8);
            s3 = *(const short8*)(p2 + (size_t)cc * 4096 + 2048 + tid * 8);
        }
        // (2) layer1(ch): weights from LDS
#pragma unroll
        for (int t = 0; t < 2; ++t) {
            f32x4 acc = {0.f, 0.f, 0.f, 0.f};
#pragma unroll
            for (int ks = 0; ks < 4; ++ks) {
                const short8 wf = *(const short8*)&wbuf[cb][((ks << 1) + t) * 512 + lane * 8];
                acc = __builtin_amdgcn_mfma_f32_16x16x32_bf16(a1f[ks], wf, acc, 0, 0, 0);
            }
            float bias = ab1r[ch * 2 + t];
#pragma unroll
            for (int r = 0; r < 4; ++r)
                h1s[w][quad * 4 + r][t * 16 + lq] = f2b(fmaxf(acc[r] + bias, 0.f));
        }
        // (3) layer2(ch): acts from h1s, weights from LDS
        const short8 a2 = *(const short8*)&h1s[w][lq][quad * 8];
#pragma unroll
        for (int nt2 = 0; nt2 < 8; ++nt2) {
            const short8 wf = *(const short8*)&wbuf[cb][4096 + nt2 * 512 + lane * 8];
            c2[nt2] = __builtin_amdgcn_mfma_f32_16x16x32_bf16(a2, wf, c2[nt2], 0, 0, 0);
        }
        // (4) write staged regs -> other buffer, barrier
        if (ch < 15) {
            *(short8*)&wbuf[nb][f0 * 512 + lane * 8] = s0;
            *(short8*)&wbuf[nb][f1 * 512 + lane * 8] = s1;
            *(short8*)&wbuf[nb][4096 + tid * 8] = s2;
            *(short8*)&wbuf[nb][4096 + 2048 + tid * 8] = s3;
        }
        __syncthreads();
    }

    // ---- softmax over the 16 neighbors + aggregate + store ----
#pragma unroll
    for (int nt2 = 0; nt2 < 8; ++nt2) {
        f32x4 s4 = c2[nt2];
        float m = fmaxf(fmaxf(s4[0], s4[1]), fmaxf(s4[2], s4[3]));
        m = fmaxf(m, __shfl_xor(m, 16));
        m = fmaxf(m, __shfl_xor(m, 32));
        float e0 = __expf(s4[0] - m), e1 = __expf(s4[1] - m);
        float e2 = __expf(s4[2] - m), e3 = __expf(s4[3] - m);
        float s = e0 + e1 + e2 + e3;
        f32x4 v4 = vg[nt2];
        float a = e0 * v4[0] + e1 * v4[1] + e2 * v4[2] + e3 * v4[3];
        s += __shfl_xor(s, 16); s += __shfl_xor(s, 32);
        a += __shfl_xor(a, 16); a += __shfl_xor(a, 32);
        if (quad == 0)
            out[(size_t)(b * DIM + nt2 * 16 + lq) * N_PTS + n] = a / s;
    }
}

extern "C" void kernel_launch(void* const* d_in, const int* in_sizes, int n_in,
                              void* d_out, int out_size, void* d_ws, size_t ws_size,
                              hipStream_t stream) {
    const float* x    = (const float*)d_in[0];
    const float* pos  = (const float*)d_in[1];
    const float* wqkv = (const float*)d_in[2];
    const float* pw1  = (const float*)d_in[3];
    const float* pb1  = (const float*)d_in[4];
    const float* pw2  = (const float*)d_in[5];
    const float* pb2  = (const float*)d_in[6];
    const float* aw1  = (const float*)d_in[7];
    const float* ab1  = (const float*)d_in[8];
    const float* aw2  = (const float*)d_in[9];
    // ab2 unused: softmax over k is invariant to per-channel bias.
    float* out = (float*)d_out;

    int B = in_sizes[0] / (DIM * N_PTS);
    int npts = B * N_PTS;                    // 1024

    char* ws = (char*)d_ws;
    float* qkv = (float*)ws;                               // npts*384 f32
    us* p1 = (us*)(ws + (size_t)npts * 384 * 4);           // 65536 us
    us* p2 = p1 + 65536;                                   // 65536 us
    us* p3 = p2 + 65536;                                   // 8192 us

    int nq = npts / 4;                       // qkv blocks
    int grid = nq + (139264 + 255) / 256;    // + 544 pack blocks
    qkv_pack_kernel<<<grid, 256, 0, stream>>>(x, wqkv, aw1, aw2, pw2,
                                              qkv, p1, p2, p3, npts);
    attn_fused_kernel<<<npts / 4, 256, 0, stream>>>(pos, qkv,
                                                    pw1, pb1, pb2,
                                                    p1, p2, p3, ab1, out);
}

// Round 14
// 99.118 us; speedup vs baseline: 1.0893x; 1.0893x over previous
//
#include <hip/hip_runtime.h>
#include <math.h>

#define DIM 128
#define N_PTS 512
#define K_NEIGH 16
#define POS_HID 64
#define ATTN_HID 512

typedef __attribute__((ext_vector_type(8))) short short8;
typedef __attribute__((ext_vector_type(4))) float f32x4;
typedef unsigned short us;
typedef unsigned long long ull;

__device__ __forceinline__ us f2b(float f) {
    unsigned int u = __builtin_bit_cast(unsigned int, f);
    u += 0x7fffu + ((u >> 16) & 1u);          // RNE
    return (us)(u >> 16);
}

__device__ __forceinline__ ull shflx64(ull v, int m) {
    int lo = __shfl_xor((int)(unsigned int)v, m);
    int hi = __shfl_xor((int)(unsigned int)(v >> 32), m);
    return ((ull)(unsigned int)hi << 32) | (unsigned int)lo;
}

// ---------------------------------------------------------------------------
// Kernel A [R9, verified 99.14]: qkv + pack merged.
// Blocks 0..npts/4-1: qkv tiles with inline wqkv->bf16 fragments.
// Blocks npts/4.. : pack aw1/aw2/pw2 -> p1/p2/p3 [R2-proven layout:
// B[k][n] -> lane l=(k/8%4)*16+(n%16), elem j=k%8, frag ks*NT+nt].
// ---------------------------------------------------------------------------
__global__ __launch_bounds__(256)
void qkv_pack_kernel(const float* __restrict__ x,
                     const float* __restrict__ wqkv,
                     const float* __restrict__ aw1,
                     const float* __restrict__ aw2,
                     const float* __restrict__ pw2,
                     float* __restrict__ qkv,
                     us* __restrict__ p1, us* __restrict__ p2,
                     us* __restrict__ p3, int npts) {
    __shared__ __align__(16) us xA[16][136];
    const int tid = threadIdx.x;
    const int nq = npts >> 2;

    if ((int)blockIdx.x >= nq) {
        int t = ((int)blockIdx.x - nq) * 256 + tid;
        if (t < 65536) {                        // aw1: ks 0..3, nt 0..31
            int j = t & 7, l = (t >> 3) & 63, nt = (t >> 9) & 31, ks = t >> 14;
            int k = ks * 32 + (l >> 4) * 8 + j, n = nt * 16 + (l & 15);
            p1[t] = f2b(aw1[k * ATTN_HID + n]);
        } else if (t < 131072) {                // aw2: ch 0..15, nt 0..7
            int u = t - 65536;
            int j = u & 7, l = (u >> 3) & 63, nt = (u >> 9) & 7, ch = u >> 12;
            int k = ch * 32 + (l >> 4) * 8 + j, n = nt * 16 + (l & 15);
            p2[u] = f2b(aw2[k * DIM + n]);
        } else if (t < 139264) {                // pw2: ks 0..1, nt 0..7
            int u = t - 131072;
            int j = u & 7, l = (u >> 3) & 63, nt = (u >> 9) & 7, ks = u >> 12;
            int k = ks * 32 + (l >> 4) * 8 + j, n = nt * 16 + (l & 15);
            p3[u] = f2b(pw2[k * DIM + n]);
        }
        return;
    }

    const int w = tid >> 6, lane = tid & 63, quad = lane >> 4, lq = lane & 15;
    const int n0 = ((int)blockIdx.x >> 2) * 16;
    const int ntb = ((int)blockIdx.x & 3) * 6;
    const int b = n0 >> 9, nn = n0 & (N_PTS - 1);
#pragma unroll
    for (int rr = 0; rr < 8; ++rr) {
        int id = rr * 256 + tid;
        int d = id >> 4, i = id & 15;
        xA[i][d] = f2b(x[(size_t)(b * DIM + d) * N_PTS + nn + i]);
    }
    __syncthreads();
    short8 a[4];
#pragma unroll
    for (int ks = 0; ks < 4; ++ks)
        a[ks] = *(const short8*)&xA[lq][ks * 32 + quad * 8];
#pragma unroll
    for (int i = 0; i < 2; ++i) {
        int nl = w + i * 4;
        if (nl < 6) {
            int nt = ntb + nl;
            f32x4 acc = {0.f, 0.f, 0.f, 0.f};
#pragma unroll
            for (int ks = 0; ks < 4; ++ks) {
                const float* wp = wqkv + (size_t)(ks * 32 + quad * 8) * 384 + nt * 16 + lq;
                short8 bf;
#pragma unroll
                for (int j = 0; j < 8; ++j) bf[j] = (short)f2b(wp[(size_t)j * 384]);
                acc = __builtin_amdgcn_mfma_f32_16x16x32_bf16(a[ks], bf, acc, 0, 0, 0);
            }
#pragma unroll
            for (int r = 0; r < 4; ++r)
                qkv[(size_t)(n0 + quad * 4 + r) * 384 + nt * 16 + lq] = acc[r];
        }
    }
}

// ---------------------------------------------------------------------------
// Fused attention [R14]: R8 structure (verified best, zero barriers, 1 wave/
// point, pipelined MLP) + chunk-0 MLP weight loads HOISTED above topk.
// R13's staging lesson: barriers are poison here; keep waves independent.
// The hoist is pure reordering: p1f[0]/p2f[0] depend on nothing in-kernel;
// their ~500cy L2 latency moves under the ~6000cy topk instead of sitting
// serially between gather and layer1(0). (+64 VGPR held; budget 512.)
// ---------------------------------------------------------------------------
__global__ __launch_bounds__(256, 1)
void attn_fused_kernel(const float* __restrict__ pos,
                       const float* __restrict__ qkv,
                       const float* __restrict__ pw1,
                       const float* __restrict__ pb1,
                       const float* __restrict__ pb2,
                       const us* __restrict__ p1,
                       const us* __restrict__ p2,
                       const us* __restrict__ p3,
                       const float* __restrict__ ab1,
                       float* __restrict__ out) {
    __shared__ __align__(16) us hinA[4][16][136];   // 17.4 KB, per-wave
    __shared__ __align__(16) us h1s[4][2][16][40];  // 10.2 KB, per-wave dbuf
    __shared__ int nbrs[4][16];                     //  256 B, per-wave

    const int tid = threadIdx.x;
    const int w = tid >> 6, lane = tid & 63, quad = lane >> 4, lq = lane & 15;
    const int g = blockIdx.x * 4 + w, b = g >> 9, n = g & (N_PTS - 1);

    // ==== hoisted loads: independent of topk, latency hides under it ====
    short8 p1f[2][2][4];   // [buf][t][ks]; buf b holds chunk with (chunk&1)==b
    short8 p2f[2][8];      // [buf][nt2]
#pragma unroll
    for (int t = 0; t < 2; ++t)                    // [R14] chunk-0 L1 weights
#pragma unroll
        for (int ks = 0; ks < 4; ++ks)
            p1f[0][t][ks] = *(const short8*)(p1 + (size_t)(((ks << 5) + t) * 64 + lane) * 8);
#pragma unroll
    for (int nt2 = 0; nt2 < 8; ++nt2)              // [R14] chunk-0 L2 weights
        p2f[0][nt2] = *(const short8*)(p2 + (size_t)(nt2 * 64 + lane) * 8);

    short8 b3f[2][8];                      // pw2 fragments
#pragma unroll
    for (int ks = 0; ks < 2; ++ks)
#pragma unroll
        for (int nt = 0; nt < 8; ++nt)
            b3f[ks][nt] = *(const short8*)(p3 + (size_t)((ks * 8 + nt) * 64 + lane) * 8);

    float w1x[2][8], w1y[2][8], w1z[2][8], w1b[2][8];   // pos-MLP layer-1 wts
#pragma unroll
    for (int ks = 0; ks < 2; ++ks)
#pragma unroll
        for (int jj = 0; jj < 8; ++jj) {
            int c = ks * 32 + quad * 8 + jj;
            w1x[ks][jj] = pw1[c];
            w1y[ks][jj] = pw1[64 + c];
            w1z[ks][jj] = pw1[128 + c];
            w1b[ks][jj] = pb1[c];
        }

    float qvr[8], pb2r[8], ab1r[32];
#pragma unroll
    for (int nt = 0; nt < 8; ++nt) {
        qvr[nt]  = qkv[(size_t)g * 384 + nt * 16 + lq];
        pb2r[nt] = pb2[nt * 16 + lq];
    }
#pragma unroll
    for (int nt = 0; nt < 32; ++nt) ab1r[nt] = ab1[nt * 16 + lq];

    // ---- top-16: u64 key = (dist_bits<<32)|j, butterfly min [R5-exact] ----
    {
        const float pix = pos[g * 3 + 0], piy = pos[g * 3 + 1], piz = pos[g * 3 + 2];
        float d2[8];
#pragma unroll
        for (int rr = 0; rr < 8; ++rr) {
            int j = rr * 64 + lane;
            float dx = pix - pos[(b * N_PTS + j) * 3 + 0];
            float dy = piy - pos[(b * N_PTS + j) * 3 + 1];
            float dz = piz - pos[(b * N_PTS + j) * 3 + 2];
            d2[rr] = dx * dx + dy * dy + dz * dz;
        }
        for (int r = 0; r < K_NEIGH; ++r) {
            ull key = ~0ULL;
#pragma unroll
            for (int rr = 0; rr < 8; ++rr) {
                unsigned int fb = __builtin_bit_cast(unsigned int, d2[rr]);
                ull k2 = ((ull)fb << 32) | (unsigned int)(rr * 64 + lane);
                key = k2 < key ? k2 : key;
            }
#pragma unroll
            for (int off = 32; off > 0; off >>= 1) {
                ull o = shflx64(key, off);
                key = o < key ? o : key;
            }
            unsigned int jw = (unsigned int)key;      // uniform post-butterfly
            if (lane == 0) nbrs[w][r] = (int)jw;
            if (lane == (int)(jw & 63)) d2[jw >> 6] = __builtin_inff();
        }
    }

    // ---- pos-MLP hidden -> A-frags (k = ks*32 + quad*8 + jj) ----
    short8 pha[2];
    {
        const int jn = nbrs[w][lq];
        float rx = pos[g * 3 + 0] - pos[(b * N_PTS + jn) * 3 + 0];
        float ry = pos[g * 3 + 1] - pos[(b * N_PTS + jn) * 3 + 1];
        float rz = pos[g * 3 + 2] - pos[(b * N_PTS + jn) * 3 + 2];
#pragma unroll
        for (int ks = 0; ks < 2; ++ks) {
            short8 f;
#pragma unroll
            for (int jj = 0; jj < 8; ++jj) {
                float h = rx * w1x[ks][jj] + ry * w1y[ks][jj] + rz * w1z[ks][jj] + w1b[ks][jj];
                f[jj] = (short)f2b(fmaxf(h, 0.f));
            }
            pha[ks] = f;
        }
    }

    // ---- pe = ph @ pw2 + pb2 (M=16,K=64,N=128) ----
    f32x4 pe[8];
#pragma unroll
    for (int nt = 0; nt < 8; ++nt) {
        f32x4 acc = {0.f, 0.f, 0.f, 0.f};
        acc = __builtin_amdgcn_mfma_f32_16x16x32_bf16(pha[0], b3f[0][nt], acc, 0, 0, 0);
        acc = __builtin_amdgcn_mfma_f32_16x16x32_bf16(pha[1], b3f[1][nt], acc, 0, 0, 0);
#pragma unroll
        for (int r = 0; r < 4; ++r) pe[nt][r] = acc[r] + pb2r[nt];
    }

    // ---- hin = q_i - k_j + pe -> LDS (bf16 A-layout); vg = v_j + pe ----
    f32x4 vg[8];
    {
        int jr[4];
#pragma unroll
        for (int r = 0; r < 4; ++r) jr[r] = nbrs[w][quad * 4 + r];
#pragma unroll
        for (int nt = 0; nt < 8; ++nt) {
            int d = nt * 16 + lq;
#pragma unroll
            for (int r = 0; r < 4; ++r) {
                const float* kv = qkv + (size_t)(b * N_PTS + jr[r]) * 384;
                float pp = pe[nt][r];
                hinA[w][quad * 4 + r][d] = f2b(qvr[nt] - kv[128 + d] + pp);
                vg[nt][r] = kv[256 + d] + pp;
            }
        }
    }

    // ---- pipelined layer1/layer2 over 16 chunks [R8] ----
    short8 a1f[4];
#pragma unroll
    for (int ks = 0; ks < 4; ++ks)
        a1f[ks] = *(const short8*)&hinA[w][lq][ks * 32 + quad * 8];

    f32x4 c2[8];
#pragma unroll
    for (int nt = 0; nt < 8; ++nt) c2[nt] = (f32x4){0.f, 0.f, 0.f, 0.f};

    // prologue: layer1(0) -> h1s buf0 (chunk-0 weights already in regs),
    // then chunk-1 L1 weights
#pragma unroll
    for (int t = 0; t < 2; ++t) {
        f32x4 acc = {0.f, 0.f, 0.f, 0.f};
#pragma unroll
        for (int ks = 0; ks < 4; ++ks)
            acc = __builtin_amdgcn_mfma_f32_16x16x32_bf16(a1f[ks], p1f[0][t][ks], acc, 0, 0, 0);
        float bias = ab1r[t];
#pragma unroll
        for (int r = 0; r < 4; ++r)
            h1s[w][0][quad * 4 + r][t * 16 + lq] = f2b(fmaxf(acc[r] + bias, 0.f));
    }
#pragma unroll
    for (int t = 0; t < 2; ++t)
#pragma unroll
        for (int ks = 0; ks < 4; ++ks)
            p1f[1][t][ks] = *(const short8*)(p1 + (size_t)(((ks << 5) + 2 + t) * 64 + lane) * 8);

#pragma unroll
    for (int ch = 0; ch < 16; ++ch) {
        const int cb = ch & 1, nb = cb ^ 1;
        // (1) early LDS read: chunk ch's acts, written one iteration ago
        const short8 a2 = *(const short8*)&h1s[w][cb][lq][quad * 8];
        // (2) prefetch L1 weights for ch+2 (into the buffer freed by layer1(ch))
        if (ch < 14) {
#pragma unroll
            for (int t = 0; t < 2; ++t)
#pragma unroll
                for (int ks = 0; ks < 4; ++ks)
                    p1f[cb][t][ks] = *(const short8*)(p1 + (size_t)(((ks << 5) + (ch + 2) * 2 + t) * 64 + lane) * 8);
        }
        // (3) prefetch L2 weights for ch+1
        if (ch < 15) {
#pragma unroll
            for (int nt2 = 0; nt2 < 8; ++nt2)
                p2f[nb][nt2] = *(const short8*)(p2 + (size_t)((((ch + 1) << 3) + nt2) * 64 + lane) * 8);
        }
        // (4) layer1 for ch+1 -> other h1s buffer (hides a2's LDS latency)
        if (ch < 15) {
#pragma unroll
            for (int t = 0; t < 2; ++t) {
                int nt = (ch + 1) * 2 + t;
                f32x4 acc = {0.f, 0.f, 0.f, 0.f};
#pragma unroll
                for (int ks = 0; ks < 4; ++ks)
                    acc = __builtin_amdgcn_mfma_f32_16x16x32_bf16(a1f[ks], p1f[nb][t][ks], acc, 0, 0, 0);
                float bias = ab1r[nt];
#pragma unroll
                for (int r = 0; r < 4; ++r)
                    h1s[w][nb][quad * 4 + r][t * 16 + lq] = f2b(fmaxf(acc[r] + bias, 0.f));
            }
        }
        // (5) layer2 for ch (8 independent accumulator chains)
#pragma unroll
        for (int nt2 = 0; nt2 < 8; ++nt2)
            c2[nt2] = __builtin_amdgcn_mfma_f32_16x16x32_bf16(a2, p2f[cb][nt2], c2[nt2], 0, 0, 0);
    }

    // ---- softmax over the 16 neighbors + aggregate + store ----
#pragma unroll
    for (int nt2 = 0; nt2 < 8; ++nt2) {
        f32x4 s4 = c2[nt2];
        float m = fmaxf(fmaxf(s4[0], s4[1]), fmaxf(s4[2], s4[3]));
        m = fmaxf(m, __shfl_xor(m, 16));
        m = fmaxf(m, __shfl_xor(m, 32));
        float e0 = __expf(s4[0] - m), e1 = __expf(s4[1] - m);
        float e2 = __expf(s4[2] - m), e3 = __expf(s4[3] - m);
        float s = e0 + e1 + e2 + e3;
        f32x4 v4 = vg[nt2];
        float a = e0 * v4[0] + e1 * v4[1] + e2 * v4[2] + e3 * v4[3];
        s += __shfl_xor(s, 16); s += __shfl_xor(s, 32);
        a += __shfl_xor(a, 16); a += __shfl_xor(a, 32);
        if (quad == 0)
            out[(size_t)(b * DIM + nt2 * 16 + lq) * N_PTS + n] = a / s;
    }
}

extern "C" void kernel_launch(void* const* d_in, const int* in_sizes, int n_in,
                              void* d_out, int out_size, void* d_ws, size_t ws_size,
                              hipStream_t stream) {
    const float* x    = (const float*)d_in[0];
    const float* pos  = (const float*)d_in[1];
    const float* wqkv = (const float*)d_in[2];
    const float* pw1  = (const float*)d_in[3];
    const float* pb1  = (const float*)d_in[4];
    const float* pw2  = (const float*)d_in[5];
    const float* pb2  = (const float*)d_in[6];
    const float* aw1  = (const float*)d_in[7];
    const float* ab1  = (const float*)d_in[8];
    const float* aw2  = (const float*)d_in[9];
    // ab2 unused: softmax over k is invariant to per-channel bias.
    float* out = (float*)d_out;

    int B = in_sizes[0] / (DIM * N_PTS);
    int npts = B * N_PTS;                    // 1024

    char* ws = (char*)d_ws;
    float* qkv = (float*)ws;                               // npts*384 f32
    us* p1 = (us*)(ws + (size_t)npts * 384 * 4);           // 65536 us
    us* p2 = p1 + 65536;                                   // 65536 us
    us* p3 = p2 + 65536;                                   // 8192 us

    int nq = npts / 4;                       // qkv blocks
    int grid = nq + (139264 + 255) / 256;    // + 544 pack blocks
    qkv_pack_kernel<<<grid, 256, 0, stream>>>(x, wqkv, aw1, aw2, pw2,
                                              qkv, p1, p2, p3, npts);
    attn_fused_kernel<<<npts / 4, 256, 0, stream>>>(pos, qkv,
                                                    pw1, pb1, pb2,
                                                    p1, p2, p3, ab1, out);
}